// Round 1
// baseline (501.421 us; speedup 1.0000x reference)
//
#include <hip/hip_runtime.h>
#include <hip/hip_bf16.h>
#include <cstdint>

// Problem constants (ViT-Base, 14x14 window + CLS)
#define BATCH 128
#define NTOK  197
#define NHEAD 12

typedef __attribute__((ext_vector_type(8))) __bf16 bf16x8;
typedef __attribute__((ext_vector_type(4))) float f32x4;
typedef __attribute__((ext_vector_type(4))) unsigned short ushort4v;

#define KSTR 72   // LDS row stride (bf16 elems) for attn tiles: uniform banks

__device__ __forceinline__ unsigned short f2bf(float f) {
    union { float f; unsigned int u; } v; v.f = f;
    unsigned int r = (v.u + 0x7FFFu + ((v.u >> 16) & 1u)) >> 16;   // RNE
    return (unsigned short)r;
}

// async global->LDS 16B per lane; LDS dest wave-uniform base + lane*16
__device__ __forceinline__ void async_cp16(const void* gsrc, void* lds_dst) {
    __builtin_amdgcn_global_load_lds(
        (const __attribute__((address_space(1))) unsigned int*)((uintptr_t)gsrc),
        (__attribute__((address_space(3))) unsigned int*)((uintptr_t)lds_dst),
        16, 0, 0);
}

// ---------------------------------------------------------------------------
// K0: bias in MFMA C/D fragment order:
//   BT[h][qt16][kt][quad][l16][j*4+r] = rpb[rel_idx[qn][kn]][h]
// ---------------------------------------------------------------------------
__global__ void bias_tiles(const float* __restrict__ rpb,
                           const int* __restrict__ rel_idx,
                           float* __restrict__ BT) {
    int idx = blockIdx.x * 256 + threadIdx.x;          // exactly 786432
    int r    = idx & 3;
    int j    = (idx >> 2) & 3;
    int l16  = (idx >> 4) & 15;
    int quad = (idx >> 8) & 3;
    int kt   = (idx >> 10) & 3;
    int qt   = (idx >> 12) & 15;
    int h    = idx >> 16;                              // 0..11
    int qn = qt * 16 + quad * 4 + r; if (qn > 196) qn = 196;
    int kn = kt * 64 + j * 16 + l16;
    float v = 0.f;
    if (kn < NTOK) v = rpb[rel_idx[qn * NTOK + kn] * NHEAD + h];
    BT[idx] = v;
}

// ---------------------------------------------------------------------------
// fp32 -> bf16 (RNE), vectorized x4
// ---------------------------------------------------------------------------
__global__ __launch_bounds__(256) void cvt_bf16(const float4* __restrict__ src,
                                                ushort4v* __restrict__ dst, int n4) {
    int i = blockIdx.x * 256 + threadIdx.x;
    if (i >= n4) return;
    float4 f = src[i];
    ushort4v o;
    o.x = f2bf(f.x); o.y = f2bf(f.y); o.z = f2bf(f.z); o.w = f2bf(f.w);
    dst[i] = o;
}

// ---------------------------------------------------------------------------
// bf16 MFMA NT GEMM, 256x256 tile, BK=64, 8 waves (2M x 4N), per-wave 128x64.
// Double-buffered 128 KiB LDS; counted vmcnt(8) keeps next tile's 8
// global_load_lds in flight across barriers (T3+T4); 4 phases/tile each
// {4 ds_read_b128 -> barrier -> 16 MFMA (setprio=1) -> barrier} (T5).
// LDS XOR-swizzle chunk^= row&7 (16B chunks), applied at the pre-swizzled
// GLOBAL source (global_load_lds writes linearly) and at the ds_read addr
// (T2) -> uniform bank load, ~0 conflicts.
// EPI=0: +qkv bias, q*=0.125, scatter BF16 q/k/v [Bc,H,N,64]
// EPI=1: +proj bias -> fp32 out [m][768]
// ---------------------------------------------------------------------------
template <int EPI>
__global__ __launch_bounds__(512, 2) void gemm_mfma(
    const unsigned short* __restrict__ A,   // [Mc][768] bf16
    const unsigned short* __restrict__ W,   // [Nn][768] bf16
    const float* __restrict__ bias1, const float* __restrict__ bias2,
    unsigned short* __restrict__ oq, unsigned short* __restrict__ ok,
    unsigned short* __restrict__ ov, float* __restrict__ outf,
    int Mc) {
    __shared__ unsigned short lds[65536];   // 2 bufs x (A 256x64 + B 256x64) = 128 KiB

    const int t    = threadIdx.x;
    const int lane = t & 63;
    const int wave = t >> 6;          // 0..7
    const int wm   = wave >> 2;       // 0..1  M half (128 rows)
    const int wn   = wave & 3;        // 0..3  N quarter (64 cols)
    const int quad = lane >> 4;
    const int l16  = lane & 15;
    const int m0   = blockIdx.y * 256;
    const int n0   = blockIdx.x * 256;

    // ---- staging addresses: load l covers tile-rows l*64+wave*8 .. +7.
    //      lane -> row r = l*64+wave*8+(lane>>3)  (so r&7 == lane>>3),
    //      LDS chunk' = lane&7 (linear);  global chunk = chunk' ^ (r&7).
    const int srow = wave * 8 + (lane >> 3);
    const int scol = (((lane & 7) ^ (lane >> 3)) << 3);      // elems within 64-slice
    const unsigned short* Asrc[4];
    const unsigned short* Wsrc[4];
#pragma unroll
    for (int l = 0; l < 4; l++) {
        int ra = m0 + l * 64 + srow; if (ra >= Mc) ra = Mc - 1;
        Asrc[l] = A + (size_t)ra * 768 + scol;
        Wsrc[l] = W + (size_t)(n0 + l * 64 + srow) * 768 + scol;
    }

    auto stage = [&](int c, int kt) {
        unsigned short* Ab = lds + c * 32768;
        unsigned short* Bb = Ab + 16384;
#pragma unroll
        for (int l = 0; l < 4; l++) {
            async_cp16(Asrc[l] + kt * 64, Ab + (l * 64 + wave * 8) * 64);
            async_cp16(Wsrc[l] + kt * 64, Bb + (l * 64 + wave * 8) * 64);
        }
    };

    // ---- fragment read offsets (elems): row = base + l16,
    //      swizzled chunk = g ^ (l16&7) with g = kk*4 + quad.
    const int arow0 = wm * 128 + l16;
    const int brow0 = wn * 64 + l16;
    const int csw0  = ((quad ^ (l16 & 7)) << 3);
    const int csw1  = (((4 + quad) ^ (l16 & 7)) << 3);

    f32x4 acc[8][4] = {};

    stage(0, 0);
#pragma unroll 1
    for (int kt = 0; kt < 12; kt++) {
        const int c = kt & 1;
        if (kt < 11) {
            stage(c ^ 1, kt + 1);                       // 8 loads for tile kt+1
            asm volatile("s_waitcnt vmcnt(8)" ::: "memory");   // tile kt landed; kt+1 in flight
        } else {
            asm volatile("s_waitcnt vmcnt(0)" ::: "memory");
        }
        __builtin_amdgcn_s_barrier();
        __builtin_amdgcn_sched_barrier(0);

        const unsigned short* Ab = lds + c * 32768;
        const unsigned short* Bb = Ab + 16384;

        bf16x8 bfr[4][2];                               // B frags held whole tile
#pragma unroll
        for (int nf = 0; nf < 4; nf++) {
            bfr[nf][0] = *(const bf16x8*)(Bb + (brow0 + nf * 16) * 64 + csw0);
            bfr[nf][1] = *(const bf16x8*)(Bb + (brow0 + nf * 16) * 64 + csw1);
        }
#pragma unroll
        for (int p = 0; p < 4; p++) {
            bf16x8 af[2][2];
#pragma unroll
            for (int i = 0; i < 2; i++) {
                af[i][0] = *(const bf16x8*)(Ab + (arow0 + (p * 2 + i) * 16) * 64 + csw0);
                af[i][1] = *(const bf16x8*)(Ab + (arow0 + (p * 2 + i) * 16) * 64 + csw1);
            }
            __builtin_amdgcn_s_barrier();
            __builtin_amdgcn_sched_barrier(0);
            __builtin_amdgcn_s_setprio(1);
#pragma unroll
            for (int kk = 0; kk < 2; kk++)
#pragma unroll
                for (int i = 0; i < 2; i++)
#pragma unroll
                    for (int nf = 0; nf < 4; nf++)
                        acc[p * 2 + i][nf] = __builtin_amdgcn_mfma_f32_16x16x32_bf16(
                            af[i][kk], bfr[nf][kk], acc[p * 2 + i][nf], 0, 0, 0);
            __builtin_amdgcn_s_setprio(0);
            __builtin_amdgcn_sched_barrier(0);
            __builtin_amdgcn_s_barrier();
        }
    }

    // ---- epilogue: C/D layout col = l16 (n), row = quad*4 + r (m) ----
    if (EPI == 0) {
        const int part   = n0 / 768;
        const float scale = (part == 0) ? 0.125f : 1.f;
        unsigned short* dst = (part == 0) ? oq : (part == 1 ? ok : ov);
        const int nb = (n0 - part * 768) + wn * 64;    // head-aligned within part
        const int h  = nb >> 6;                        // one head per wave
#pragma unroll
        for (int nf = 0; nf < 4; nf++) {
            const int d = nf * 16 + l16;
            const float bb = (part == 0) ? bias1[nb + nf * 16 + l16]
                           : (part == 2 ? bias2[nb + nf * 16 + l16] : 0.f);
#pragma unroll
            for (int mf = 0; mf < 8; mf++) {
                const int mb = m0 + wm * 128 + mf * 16 + quad * 4;
#pragma unroll
                for (int r = 0; r < 4; r++) {
                    const int m = mb + r;
                    if (m < Mc) {
                        const int bi  = m / NTOK;
                        const int tok = m - bi * NTOK;
                        dst[(((size_t)bi * NHEAD + h) * NTOK + tok) * 64 + d] =
                            f2bf((acc[mf][nf][r] + bb) * scale);
                    }
                }
            }
        }
    } else {
#pragma unroll
        for (int nf = 0; nf < 4; nf++) {
            const int col = n0 + wn * 64 + nf * 16 + l16;
            const float bb = bias1[col];
#pragma unroll
            for (int mf = 0; mf < 8; mf++) {
                const int mb = m0 + wm * 128 + mf * 16 + quad * 4;
#pragma unroll
                for (int r = 0; r < 4; r++) {
                    const int m = mb + r;
                    if (m < Mc) outf[(size_t)m * 768 + col] = acc[mf][nf][r] + bb;
                }
            }
        }
    }
}

// ---------------------------------------------------------------------------
// K2: MFMA flash attention. One block per (b,h); 4 waves x 64 q-rows.
//   S = q.k^T (acc initialized with rpb fragments), fixed-max softmax,
//   P -> per-wave LDS (C/D -> A-layout), O += P.V via MFMA. Fp32 l-sum,
//   reduced once at the end. All LDS rows stride KSTR=72 (uniform banks).
// ---------------------------------------------------------------------------
__global__ __launch_bounds__(256, 2) void attn_mfma(
    const unsigned short* __restrict__ Q, const unsigned short* __restrict__ K,
    const unsigned short* __restrict__ V, const float* __restrict__ BT,
    unsigned short* __restrict__ AO) {
    __shared__ unsigned short Ks[64 * KSTR];       // K-tile  [key][d]
    __shared__ unsigned short Vt[64 * KSTR];       // V-tile^T [d][key]
    __shared__ unsigned short Ps[4][64 * KSTR];    // per-wave P [q][key]

    const int t    = threadIdx.x;
    const int lane = t & 63;
    const int wave = t >> 6;
    const int quad = lane >> 4;
    const int l16  = lane & 15;
    const int bh   = blockIdx.x;
    const int b    = bh / NHEAD;
    const int h    = bh - b * NHEAD;

    const unsigned short* qb = Q + (size_t)bh * NTOK * 64;
    const unsigned short* kb = K + (size_t)bh * NTOK * 64;
    const unsigned short* vb = V + (size_t)bh * NTOK * 64;

    // Q fragments in registers for the whole kernel (A-layout: m=l16, k=quad*8+j)
    bf16x8 qf[4][2];
#pragma unroll
    for (int i = 0; i < 4; i++) {
        int tok = wave * 64 + i * 16 + l16; if (tok > 196) tok = 196;
#pragma unroll
        for (int ks = 0; ks < 2; ks++)
            qf[i][ks] = *(const bf16x8*)&qb[(size_t)tok * 64 + ks * 32 + quad * 8];
    }

    f32x4 O[4][4] = {};
    float lsum[4][4] = {};        // [i][r]

    for (int kt = 0; kt < 4; kt++) {
        __syncthreads();          // prior iteration's Ks/Vt reads complete
        {   // stage Ks [key][d], stride 72: thread -> row t>>2, 32B chunk t&3
            const int row = t >> 2, cg = t & 3;
            int gk = kt * 64 + row; if (gk > 196) gk = 196;
            const uint4* src = (const uint4*)&kb[(size_t)gk * 64 + cg * 16];
            *(uint4*)&Ks[row * KSTR + cg * 16]     = src[0];
            *(uint4*)&Ks[row * KSTR + cg * 16 + 8] = src[1];
        }
        {   // stage Vt [d][key] transposed: thread -> key t&63, d-group t>>6
            const int key = t & 63, dg = t >> 6;
            int gk = kt * 64 + key; if (gk > 196) gk = 196;
            union { uint4 v4[2]; unsigned short u[16]; } tmp;
            const uint4* src = (const uint4*)&vb[(size_t)gk * 64 + dg * 16];
            tmp.v4[0] = src[0]; tmp.v4[1] = src[1];
#pragma unroll
            for (int u = 0; u < 16; u++) Vt[(dg * 16 + u) * KSTR + key] = tmp.u[u];
        }
        __syncthreads();

        // ---- acc init = rpb fragments (coalesced dwordx4, L2-hit) ----
        f32x4 acc[4][4];
#pragma unroll
        for (int i = 0; i < 4; i++) {
            const float4* bp = (const float4*)&BT[
                (((((size_t)h * 16 + (wave * 4 + i)) * 4 + kt) * 4 + quad) * 16 + l16) * 16];
#pragma unroll
            for (int j = 0; j < 4; j++) {
                float4 f = bp[j];
                acc[i][j] = (f32x4){f.x, f.y, f.z, f.w};
            }
        }

        // ---- S = q.k^T + bias ----
#pragma unroll
        for (int ks = 0; ks < 2; ks++) {
            bf16x8 kf[4];
#pragma unroll
            for (int j = 0; j < 4; j++)
                kf[j] = *(const bf16x8*)&Ks[(j * 16 + l16) * KSTR + ks * 32 + quad * 8];
#pragma unroll
            for (int i = 0; i < 4; i++)
#pragma unroll
                for (int j = 0; j < 4; j++)
                    acc[i][j] = __builtin_amdgcn_mfma_f32_16x16x32_bf16(
                        qf[i][ks], kf[j], acc[i][j], 0, 0, 0);
        }

        // ---- fixed-max softmax: p = exp(s), masked keys -> 0; write P ----
#pragma unroll
        for (int j = 0; j < 4; j++) {
            const int kn = kt * 64 + j * 16 + l16;
            const bool kval = (kn < NTOK);
#pragma unroll
            for (int i = 0; i < 4; i++)
#pragma unroll
                for (int r = 0; r < 4; r++) {
                    float p = kval ? __expf(fminf(acc[i][j][r], 30.f)) : 0.f;
                    lsum[i][r] += p;
                    Ps[wave][(i * 16 + quad * 4 + r) * KSTR + j * 16 + l16] = f2bf(p);
                }
        }
        // in-wave LDS write->read ordering: compiler inserts lgkmcnt; no barrier
        // needed (Ps[wave] is wave-private).

        // ---- O += P.V ----
#pragma unroll
        for (int ks = 0; ks < 2; ks++) {
            bf16x8 vf[4], pf[4];
#pragma unroll
            for (int jd = 0; jd < 4; jd++)
                vf[jd] = *(const bf16x8*)&Vt[(jd * 16 + l16) * KSTR + ks * 32 + quad * 8];
#pragma unroll
            for (int i = 0; i < 4; i++)
                pf[i] = *(const bf16x8*)&Ps[wave][(i * 16 + l16) * KSTR + ks * 32 + quad * 8];
#pragma unroll
            for (int i = 0; i < 4; i++)
#pragma unroll
                for (int jd = 0; jd < 4; jd++)
                    O[i][jd] = __builtin_amdgcn_mfma_f32_16x16x32_bf16(
                        pf[i], vf[jd], O[i][jd], 0, 0, 0);
        }
    }

    // ---- l-sum reduction across the 16-lane col groups, then store ----
#pragma unroll
    for (int i = 0; i < 4; i++)
#pragma unroll
        for (int r = 0; r < 4; r++) {
            float l = lsum[i][r];
            l += __shfl_xor(l, 1); l += __shfl_xor(l, 2);
            l += __shfl_xor(l, 4); l += __shfl_xor(l, 8);
            lsum[i][r] = 1.f / l;
        }
#pragma unroll
    for (int i = 0; i < 4; i++) {
        const int tb = wave * 64 + i * 16 + quad * 4;
#pragma unroll
        for (int r = 0; r < 4; r++) {
            const int tok = tb + r;
            if (tok < NTOK) {
                const float rl = lsum[i][r];
#pragma unroll
                for (int jd = 0; jd < 4; jd++)
                    AO[((size_t)b * NTOK + tok) * 768 + h * 64 + jd * 16 + l16] =
                        f2bf(O[i][jd][r] * rl);
            }
        }
    }
}

// ---------------------------------------------------------------------------
extern "C" void kernel_launch(void* const* d_in, const int* in_sizes, int n_in,
                              void* d_out, int out_size, void* d_ws, size_t ws_size,
                              hipStream_t stream) {
    const float* x      = (const float*)d_in[0];
    const float* qkv_w  = (const float*)d_in[1];
    const float* q_bias = (const float*)d_in[2];
    const float* v_bias = (const float*)d_in[3];
    const float* rpb    = (const float*)d_in[4];
    const float* proj_w = (const float*)d_in[5];
    const float* proj_b = (const float*)d_in[6];
    const int*   rel_idx = (const int*)d_in[7];
    float* out = (float*)d_out;

    const size_t EB   = 151296;                    // 12*197*64 = 197*768
    const size_t NBT  = 786432;                    // bias tiles (floats)
    const size_t NX   = (size_t)BATCH * NTOK * 768;
    const size_t NWQ  = (size_t)2304 * 768;
    const size_t NWP  = (size_t)768 * 768;

    // layout: BT(f32) | xbf | wqkv | wproj | q,k,v,ao (all bf16)
    const size_t fixed_bytes = NBT * 4 + (NX + NWQ + NWP) * 2;
    int Bc = BATCH;
    while (Bc > 1 && fixed_bytes + 8ull * Bc * EB > ws_size) Bc >>= 1;
    if (fixed_bytes + 8ull * Bc * EB > ws_size) return;
    const int nc = BATCH / Bc;
    const int Mc = Bc * NTOK;
    const int Gy = (Mc + 255) / 256;

    float* BT             = (float*)d_ws;
    unsigned short* xbf   = (unsigned short*)(BT + NBT);
    unsigned short* wqkv  = xbf + NX;
    unsigned short* wproj = wqkv + NWQ;
    unsigned short* q     = wproj + NWP;
    unsigned short* k     = q + (size_t)Bc * EB;
    unsigned short* v     = k + (size_t)Bc * EB;
    unsigned short* aobf  = v + (size_t)Bc * EB;

    bias_tiles<<<(int)(NBT / 256), 256, 0, stream>>>(rpb, rel_idx, BT);
    cvt_bf16<<<(int)((NX / 4 + 255) / 256), 256, 0, stream>>>(
        (const float4*)x, (ushort4v*)xbf, (int)(NX / 4));
    cvt_bf16<<<(int)((NWQ / 4 + 255) / 256), 256, 0, stream>>>(
        (const float4*)qkv_w, (ushort4v*)wqkv, (int)(NWQ / 4));
    cvt_bf16<<<(int)((NWP / 4 + 255) / 256), 256, 0, stream>>>(
        (const float4*)proj_w, (ushort4v*)wproj, (int)(NWP / 4));

    for (int c = 0; c < nc; c++) {
        gemm_mfma<0><<<dim3(2304 / 256, Gy), 512, 0, stream>>>(
            xbf + (size_t)c * Mc * 768, wqkv, q_bias, v_bias, q, k, v, nullptr, Mc);
        attn_mfma<<<Bc * NHEAD, 256, 0, stream>>>(q, k, v, BT, aobf);
        gemm_mfma<1><<<dim3(768 / 256, Gy), 512, 0, stream>>>(
            aobf, wproj, proj_b, nullptr, nullptr, nullptr, nullptr,
            out + (size_t)c * Mc * 768, Mc);
    }
}

// Round 2
// 477.504 us; speedup vs baseline: 1.0501x; 1.0501x over previous
//
#include <hip/hip_runtime.h>
#include <hip/hip_bf16.h>
#include <cstdint>

// Problem constants (ViT-Base, 14x14 window + CLS)
#define BATCH 128
#define NTOK  197
#define NHEAD 12

typedef __attribute__((ext_vector_type(8))) __bf16 bf16x8;
typedef __attribute__((ext_vector_type(4))) float f32x4;
typedef __attribute__((ext_vector_type(4))) unsigned short ushort4v;

#define KSTR 72   // LDS row stride (bf16 elems) for attn tiles: uniform banks

__device__ __forceinline__ unsigned short f2bf(float f) {
    union { float f; unsigned int u; } v; v.f = f;
    unsigned int r = (v.u + 0x7FFFu + ((v.u >> 16) & 1u)) >> 16;   // RNE
    return (unsigned short)r;
}

// async global->LDS 16B per lane; LDS dest wave-uniform base + lane*16
__device__ __forceinline__ void async_cp16(const void* gsrc, void* lds_dst) {
    __builtin_amdgcn_global_load_lds(
        (const __attribute__((address_space(1))) unsigned int*)((uintptr_t)gsrc),
        (__attribute__((address_space(3))) unsigned int*)((uintptr_t)lds_dst),
        16, 0, 0);
}

// ---------------------------------------------------------------------------
// K0: bias in MFMA C/D fragment order:
//   BT[h][qt16][kt][quad][l16][j*4+r] = rpb[rel_idx[qn][kn]][h]
// ---------------------------------------------------------------------------
__global__ void bias_tiles(const float* __restrict__ rpb,
                           const int* __restrict__ rel_idx,
                           float* __restrict__ BT) {
    int idx = blockIdx.x * 256 + threadIdx.x;          // exactly 786432
    int r    = idx & 3;
    int j    = (idx >> 2) & 3;
    int l16  = (idx >> 4) & 15;
    int quad = (idx >> 8) & 3;
    int kt   = (idx >> 10) & 3;
    int qt   = (idx >> 12) & 15;
    int h    = idx >> 16;                              // 0..11
    int qn = qt * 16 + quad * 4 + r; if (qn > 196) qn = 196;
    int kn = kt * 64 + j * 16 + l16;
    float v = 0.f;
    if (kn < NTOK) v = rpb[rel_idx[qn * NTOK + kn] * NHEAD + h];
    BT[idx] = v;
}

// ---------------------------------------------------------------------------
// fp32 -> bf16 (RNE), vectorized x4
// ---------------------------------------------------------------------------
__global__ __launch_bounds__(256) void cvt_bf16(const float4* __restrict__ src,
                                                ushort4v* __restrict__ dst, int n4) {
    int i = blockIdx.x * 256 + threadIdx.x;
    if (i >= n4) return;
    float4 f = src[i];
    ushort4v o;
    o.x = f2bf(f.x); o.y = f2bf(f.y); o.z = f2bf(f.z); o.w = f2bf(f.w);
    dst[i] = o;
}

// ---------------------------------------------------------------------------
// bf16 MFMA NT GEMM, 256x256 tile, BK=64, 8 waves (2M x 4N), per-wave 128x64.
// 8-phase-style schedule (4 phases/K-tile):
//   phase p: {4 ds_read_b128 A-frags (+8 B-frags at p0) | staggered staging
//             (2 gloads/wave at p0, 2 at p1, for tile kt+1 into the buffer
//             holding dead tile kt-1) -> s_barrier -> lgkmcnt(0) ->
//             sched_barrier -> setprio(1) -> 16 MFMA -> setprio(0)}
//   tile boundary: vmcnt(0) (loads issued >=3 phases earlier) + s_barrier.
// LDS XOR-swizzle (T2): chunk ^= row&7, pre-swizzled global src + swizzled
// ds_read addr -> 0 bank conflicts (verified R1). T1 bijective XCD swizzle.
// EPI=0: +qkv bias, q*=0.125, scatter BF16 q/k/v [Bc,H,N,64]
// EPI=1: +proj bias -> fp32 out [m][768]
// ---------------------------------------------------------------------------
template <int EPI>
__global__ __launch_bounds__(512, 2) void gemm_mfma(
    const unsigned short* __restrict__ A,   // [Mc][768] bf16
    const unsigned short* __restrict__ W,   // [Nn][768] bf16
    const float* __restrict__ bias1, const float* __restrict__ bias2,
    unsigned short* __restrict__ oq, unsigned short* __restrict__ ok,
    unsigned short* __restrict__ ov, float* __restrict__ outf,
    int Mc) {
    __shared__ unsigned short lds[65536];   // 2 bufs x (A 256x64 + B 256x64) = 128 KiB

    const int t    = threadIdx.x;
    const int lane = t & 63;
    const int wave = t >> 6;          // 0..7
    const int wm   = wave >> 2;       // 0..1  M half (128 rows)
    const int wn   = wave & 3;        // 0..3  N quarter (64 cols)
    const int quad = lane >> 4;
    const int l16  = lane & 15;

    // ---- T1: bijective XCD-aware block swizzle (m204) ----
    const int gx  = gridDim.x;
    const int nwg = gx * gridDim.y;
    const int orig = blockIdx.y * gx + blockIdx.x;
    const int q8 = nwg >> 3, r8 = nwg & 7;
    const int xcd = orig & 7, rest = orig >> 3;
    const int wg = (xcd < r8 ? xcd * (q8 + 1) : r8 * (q8 + 1) + (xcd - r8) * q8) + rest;
    const int m0 = (wg / gx) * 256;
    const int n0 = (wg % gx) * 256;

    // ---- staging addresses (verified R1): per half-tile ht (128 rows x 64 K),
    //      2 instr/wave: instr i covers rows i*64 + wave*8 + (lane>>3).
    //      LDS linear [row][chunk]; global chunk = (lane&7) ^ (lane>>3) (T2).
    const int srow = wave * 8 + (lane >> 3);
    const int scol = (((lane & 7) ^ (lane >> 3)) << 3);      // elems
    const unsigned short* gsrc[4][2];
#pragma unroll
    for (int hh = 0; hh < 2; hh++)
#pragma unroll
        for (int i = 0; i < 2; i++) {
            int ra = m0 + hh * 128 + i * 64 + srow; if (ra >= Mc) ra = Mc - 1;
            gsrc[hh][i]     = A + (size_t)ra * 768 + scol;
            gsrc[2 + hh][i] = W + (size_t)(n0 + hh * 128 + i * 64 + srow) * 768 + scol;
        }

    // stage half-tile ht of K-tile kt into buffer b (ht: 0=A0,1=A1,2=B0,3=B1)
    auto stageHalf = [&](int b, int kt, int ht) {
        unsigned short* dst = lds + b * 32768 + ht * 8192;
        async_cp16(gsrc[ht][0] + kt * 64, dst + (wave * 8) * 64);
        async_cp16(gsrc[ht][1] + kt * 64, dst + (64 + wave * 8) * 64);
    };

    // ---- fragment read offsets (elems): swizzled chunk = g ^ (l16&7) ----
    const int csw0 = ((quad ^ (l16 & 7)) << 3);
    const int csw1 = (((4 + quad) ^ (l16 & 7)) << 3);
    const int brow = (wn & 1) * 64 + l16;

    f32x4 acc[8][4] = {};

    // prologue: tile 0 -> buffer 0, full drain (once)
#pragma unroll
    for (int ht = 0; ht < 4; ht++) stageHalf(0, 0, ht);
    asm volatile("s_waitcnt vmcnt(0)" ::: "memory");
    __builtin_amdgcn_s_barrier();

#pragma unroll 2
    for (int kt = 0; kt < 12; kt++) {
        const int b = kt & 1;
        const unsigned short* Ah = lds + b * 32768 + wm * 8192;
        const unsigned short* Bh = lds + b * 32768 + 16384 + (wn >> 1) * 8192;
        bf16x8 bfr[4][2];
#pragma unroll
        for (int p = 0; p < 4; p++) {
            bf16x8 af[2][2];
#pragma unroll
            for (int i = 0; i < 2; i++) {
                const int r = (p * 2 + i) * 16 + l16;
                af[i][0] = *(const bf16x8*)(Ah + r * 64 + csw0);
                af[i][1] = *(const bf16x8*)(Ah + r * 64 + csw1);
            }
            if (p == 0) {
#pragma unroll
                for (int nf = 0; nf < 4; nf++) {
                    bfr[nf][0] = *(const bf16x8*)(Bh + (brow + nf * 16) * 64 + csw0);
                    bfr[nf][1] = *(const bf16x8*)(Bh + (brow + nf * 16) * 64 + csw1);
                }
                if (kt < 11) { stageHalf(b ^ 1, kt + 1, 2); stageHalf(b ^ 1, kt + 1, 3); }
            } else if (p == 1) {
                if (kt < 11) { stageHalf(b ^ 1, kt + 1, 0); stageHalf(b ^ 1, kt + 1, 1); }
            }
            __builtin_amdgcn_s_barrier();
            asm volatile("s_waitcnt lgkmcnt(0)" ::: "memory");
            __builtin_amdgcn_sched_barrier(0);
            __builtin_amdgcn_s_setprio(1);
#pragma unroll
            for (int kk = 0; kk < 2; kk++)
#pragma unroll
                for (int i = 0; i < 2; i++)
#pragma unroll
                    for (int nf = 0; nf < 4; nf++)
                        acc[p * 2 + i][nf] = __builtin_amdgcn_mfma_f32_16x16x32_bf16(
                            af[i][kk], bfr[nf][kk], acc[p * 2 + i][nf], 0, 0, 0);
            __builtin_amdgcn_s_setprio(0);
        }
        // tile boundary: staged loads (issued at p0/p1) drained; buffer swap
        asm volatile("s_waitcnt vmcnt(0)" ::: "memory");
        __builtin_amdgcn_s_barrier();
    }

    // ---- epilogue: C/D layout col = l16 (n), row = quad*4 + r (m) ----
    if (EPI == 0) {
        const int part   = n0 / 768;
        const float scale = (part == 0) ? 0.125f : 1.f;
        unsigned short* dst = (part == 0) ? oq : (part == 1 ? ok : ov);
        const int nb = (n0 - part * 768) + wn * 64;    // head-aligned within part
        const int h  = nb >> 6;                        // one head per wave
#pragma unroll
        for (int nf = 0; nf < 4; nf++) {
            const int d = nf * 16 + l16;
            const float bb = (part == 0) ? bias1[nb + nf * 16 + l16]
                           : (part == 2 ? bias2[nb + nf * 16 + l16] : 0.f);
#pragma unroll
            for (int mf = 0; mf < 8; mf++) {
                const int mb = m0 + wm * 128 + mf * 16 + quad * 4;
#pragma unroll
                for (int r = 0; r < 4; r++) {
                    const int m = mb + r;
                    if (m < Mc) {
                        const int bi  = m / NTOK;
                        const int tok = m - bi * NTOK;
                        dst[(((size_t)bi * NHEAD + h) * NTOK + tok) * 64 + d] =
                            f2bf((acc[mf][nf][r] + bb) * scale);
                    }
                }
            }
        }
    } else {
#pragma unroll
        for (int nf = 0; nf < 4; nf++) {
            const int col = n0 + wn * 64 + nf * 16 + l16;
            const float bb = bias1[col];
#pragma unroll
            for (int mf = 0; mf < 8; mf++) {
                const int mb = m0 + wm * 128 + mf * 16 + quad * 4;
#pragma unroll
                for (int r = 0; r < 4; r++) {
                    const int m = mb + r;
                    if (m < Mc) outf[(size_t)m * 768 + col] = acc[mf][nf][r] + bb;
                }
            }
        }
    }
}

// ---------------------------------------------------------------------------
// K2: MFMA flash attention. One block per (b,h); 4 waves x 64 q-rows.
//   S = q.k^T (acc initialized with rpb fragments), fixed-max softmax,
//   P -> per-wave LDS (C/D -> A-layout), O += P.V via MFMA. Fp32 l-sum,
//   reduced once at the end. All LDS rows stride KSTR=72 (uniform banks).
// ---------------------------------------------------------------------------
__global__ __launch_bounds__(256, 2) void attn_mfma(
    const unsigned short* __restrict__ Q, const unsigned short* __restrict__ K,
    const unsigned short* __restrict__ V, const float* __restrict__ BT,
    unsigned short* __restrict__ AO) {
    __shared__ unsigned short Ks[64 * KSTR];       // K-tile  [key][d]
    __shared__ unsigned short Vt[64 * KSTR];       // V-tile^T [d][key]
    __shared__ unsigned short Ps[4][64 * KSTR];    // per-wave P [q][key]

    const int t    = threadIdx.x;
    const int lane = t & 63;
    const int wave = t >> 6;
    const int quad = lane >> 4;
    const int l16  = lane & 15;
    const int bh   = blockIdx.x;
    const int b    = bh / NHEAD;
    const int h    = bh - b * NHEAD;

    const unsigned short* qb = Q + (size_t)bh * NTOK * 64;
    const unsigned short* kb = K + (size_t)bh * NTOK * 64;
    const unsigned short* vb = V + (size_t)bh * NTOK * 64;

    // Q fragments in registers for the whole kernel (A-layout: m=l16, k=quad*8+j)
    bf16x8 qf[4][2];
#pragma unroll
    for (int i = 0; i < 4; i++) {
        int tok = wave * 64 + i * 16 + l16; if (tok > 196) tok = 196;
#pragma unroll
        for (int ks = 0; ks < 2; ks++)
            qf[i][ks] = *(const bf16x8*)&qb[(size_t)tok * 64 + ks * 32 + quad * 8];
    }

    f32x4 O[4][4] = {};
    float lsum[4][4] = {};        // [i][r]

    for (int kt = 0; kt < 4; kt++) {
        __syncthreads();          // prior iteration's Ks/Vt reads complete
        {   // stage Ks [key][d], stride 72: thread -> row t>>2, 32B chunk t&3
            const int row = t >> 2, cg = t & 3;
            int gk = kt * 64 + row; if (gk > 196) gk = 196;
            const uint4* src = (const uint4*)&kb[(size_t)gk * 64 + cg * 16];
            *(uint4*)&Ks[row * KSTR + cg * 16]     = src[0];
            *(uint4*)&Ks[row * KSTR + cg * 16 + 8] = src[1];
        }
        {   // stage Vt [d][key] transposed: thread -> key t&63, d-group t>>6
            const int key = t & 63, dg = t >> 6;
            int gk = kt * 64 + key; if (gk > 196) gk = 196;
            union { uint4 v4[2]; unsigned short u[16]; } tmp;
            const uint4* src = (const uint4*)&vb[(size_t)gk * 64 + dg * 16];
            tmp.v4[0] = src[0]; tmp.v4[1] = src[1];
#pragma unroll
            for (int u = 0; u < 16; u++) Vt[(dg * 16 + u) * KSTR + key] = tmp.u[u];
        }
        __syncthreads();

        // ---- acc init = rpb fragments (coalesced dwordx4, L2-hit) ----
        f32x4 acc[4][4];
#pragma unroll
        for (int i = 0; i < 4; i++) {
            const float4* bp = (const float4*)&BT[
                (((((size_t)h * 16 + (wave * 4 + i)) * 4 + kt) * 4 + quad) * 16 + l16) * 16];
#pragma unroll
            for (int j = 0; j < 4; j++) {
                float4 f = bp[j];
                acc[i][j] = (f32x4){f.x, f.y, f.z, f.w};
            }
        }

        // ---- S = q.k^T + bias ----
#pragma unroll
        for (int ks = 0; ks < 2; ks++) {
            bf16x8 kf[4];
#pragma unroll
            for (int j = 0; j < 4; j++)
                kf[j] = *(const bf16x8*)&Ks[(j * 16 + l16) * KSTR + ks * 32 + quad * 8];
#pragma unroll
            for (int i = 0; i < 4; i++)
#pragma unroll
                for (int j = 0; j < 4; j++)
                    acc[i][j] = __builtin_amdgcn_mfma_f32_16x16x32_bf16(
                        qf[i][ks], kf[j], acc[i][j], 0, 0, 0);
        }

        // ---- fixed-max softmax: p = exp(s), masked keys -> 0; write P ----
#pragma unroll
        for (int j = 0; j < 4; j++) {
            const int kn = kt * 64 + j * 16 + l16;
            const bool kval = (kn < NTOK);
#pragma unroll
            for (int i = 0; i < 4; i++)
#pragma unroll
                for (int r = 0; r < 4; r++) {
                    float p = kval ? __expf(fminf(acc[i][j][r], 30.f)) : 0.f;
                    lsum[i][r] += p;
                    Ps[wave][(i * 16 + quad * 4 + r) * KSTR + j * 16 + l16] = f2bf(p);
                }
        }
        // in-wave LDS write->read ordering: compiler inserts lgkmcnt; no barrier
        // needed (Ps[wave] is wave-private).

        // ---- O += P.V ----
#pragma unroll
        for (int ks = 0; ks < 2; ks++) {
            bf16x8 vf[4], pf[4];
#pragma unroll
            for (int jd = 0; jd < 4; jd++)
                vf[jd] = *(const bf16x8*)&Vt[(jd * 16 + l16) * KSTR + ks * 32 + quad * 8];
#pragma unroll
            for (int i = 0; i < 4; i++)
                pf[i] = *(const bf16x8*)&Ps[wave][(i * 16 + l16) * KSTR + ks * 32 + quad * 8];
#pragma unroll
            for (int i = 0; i < 4; i++)
#pragma unroll
                for (int jd = 0; jd < 4; jd++)
                    O[i][jd] = __builtin_amdgcn_mfma_f32_16x16x32_bf16(
                        pf[i], vf[jd], O[i][jd], 0, 0, 0);
        }
    }

    // ---- l-sum reduction across the 16-lane col groups, then store ----
#pragma unroll
    for (int i = 0; i < 4; i++)
#pragma unroll
        for (int r = 0; r < 4; r++) {
            float l = lsum[i][r];
            l += __shfl_xor(l, 1); l += __shfl_xor(l, 2);
            l += __shfl_xor(l, 4); l += __shfl_xor(l, 8);
            lsum[i][r] = 1.f / l;
        }
#pragma unroll
    for (int i = 0; i < 4; i++) {
        const int tb = wave * 64 + i * 16 + quad * 4;
#pragma unroll
        for (int r = 0; r < 4; r++) {
            const int tok = tb + r;
            if (tok < NTOK) {
                const float rl = lsum[i][r];
#pragma unroll
                for (int jd = 0; jd < 4; jd++)
                    AO[((size_t)b * NTOK + tok) * 768 + h * 64 + jd * 16 + l16] =
                        f2bf(O[i][jd][r] * rl);
            }
        }
    }
}

// ---------------------------------------------------------------------------
extern "C" void kernel_launch(void* const* d_in, const int* in_sizes, int n_in,
                              void* d_out, int out_size, void* d_ws, size_t ws_size,
                              hipStream_t stream) {
    const float* x      = (const float*)d_in[0];
    const float* qkv_w  = (const float*)d_in[1];
    const float* q_bias = (const float*)d_in[2];
    const float* v_bias = (const float*)d_in[3];
    const float* rpb    = (const float*)d_in[4];
    const float* proj_w = (const float*)d_in[5];
    const float* proj_b = (const float*)d_in[6];
    const int*   rel_idx = (const int*)d_in[7];
    float* out = (float*)d_out;

    const size_t EB   = 151296;                    // 12*197*64 = 197*768
    const size_t NBT  = 786432;                    // bias tiles (floats)
    const size_t NX   = (size_t)BATCH * NTOK * 768;
    const size_t NWQ  = (size_t)2304 * 768;
    const size_t NWP  = (size_t)768 * 768;

    // layout: BT(f32) | xbf | wqkv | wproj | q,k,v,ao (all bf16)
    const size_t fixed_bytes = NBT * 4 + (NX + NWQ + NWP) * 2;
    int Bc = BATCH;
    while (Bc > 1 && fixed_bytes + 8ull * Bc * EB > ws_size) Bc >>= 1;
    if (fixed_bytes + 8ull * Bc * EB > ws_size) return;
    const int nc = BATCH / Bc;
    const int Mc = Bc * NTOK;
    const int Gy = (Mc + 255) / 256;

    float* BT             = (float*)d_ws;
    unsigned short* xbf   = (unsigned short*)(BT + NBT);
    unsigned short* wqkv  = xbf + NX;
    unsigned short* wproj = wqkv + NWQ;
    unsigned short* q     = wproj + NWP;
    unsigned short* k     = q + (size_t)Bc * EB;
    unsigned short* v     = k + (size_t)Bc * EB;
    unsigned short* aobf  = v + (size_t)Bc * EB;

    bias_tiles<<<(int)(NBT / 256), 256, 0, stream>>>(rpb, rel_idx, BT);
    cvt_bf16<<<(int)((NX / 4 + 255) / 256), 256, 0, stream>>>(
        (const float4*)x, (ushort4v*)xbf, (int)(NX / 4));
    cvt_bf16<<<(int)((NWQ / 4 + 255) / 256), 256, 0, stream>>>(
        (const float4*)qkv_w, (ushort4v*)wqkv, (int)(NWQ / 4));
    cvt_bf16<<<(int)((NWP / 4 + 255) / 256), 256, 0, stream>>>(
        (const float4*)proj_w, (ushort4v*)wproj, (int)(NWP / 4));

    for (int c = 0; c < nc; c++) {
        gemm_mfma<0><<<dim3(2304 / 256, Gy), 512, 0, stream>>>(
            xbf + (size_t)c * Mc * 768, wqkv, q_bias, v_bias, q, k, v, nullptr, Mc);
        attn_mfma<<<Bc * NHEAD, 256, 0, stream>>>(q, k, v, BT, aobf);
        gemm_mfma<1><<<dim3(768 / 256, Gy), 512, 0, stream>>>(
            aobf, wproj, proj_b, nullptr, nullptr, nullptr, nullptr,
            out + (size_t)c * Mc * 768, Mc);
    }
}